// Round 4
// baseline (571.873 us; speedup 1.0000x reference)
//
#include <hip/hip_runtime.h>
#include <math.h>

#define S_TOK 8192
#define DDIM 2048
#define HDIM 2048
#define NE 8
#define CAP 2048
#define NBATCH 4
#define TT 2048

typedef _Float16 f16;
typedef _Float16 f16x4 __attribute__((ext_vector_type(4)));
typedef _Float16 f16x8 __attribute__((ext_vector_type(8)));
typedef float f32x4 __attribute__((ext_vector_type(4)));

typedef __attribute__((address_space(1))) const void* gas_ptr;
typedef __attribute__((address_space(3))) void* las_ptr;

// ---------------- K1: fused independent prep (unchanged from R3) ----------------
#define W1T_BLOCKS 8192
#define W2S_BLOCKS 4096
#define GATE_BASE (W1T_BLOCKS + W2S_BLOCKS + 1)
#define K1_GRID (GATE_BASE + S_TOK / 4)

__global__ __launch_bounds__(256) void prep_kernel(const float* __restrict__ w1,
                                                   const float* __restrict__ w2,
                                                   const float* __restrict__ b2,
                                                   const float* __restrict__ x,
                                                   const float* __restrict__ wg,
                                                   int* __restrict__ eid,
                                                   float* __restrict__ wts,
                                                   int* __restrict__ slot_token,
                                                   float* __restrict__ zacc,
                                                   f16* __restrict__ W1T,
                                                   float* __restrict__ w2s,
                                                   float* __restrict__ b2s) {
  __shared__ float tile[64 * 65];
  int bid = blockIdx.x, tid = threadIdx.x;
  if (bid >= GATE_BASE) {
    int g = bid - GATE_BASE;
    if (g < 64) {
      int i = g * 256 + tid;
      slot_token[i] = 0;
      zacc[i] = 0.f;
    }
    int wid = tid >> 6;
    int lane = tid & 63;
    int s = g * 4 + wid;
    const float* xr = x + (size_t)s * DDIM;
    double acc[8];
#pragma unroll
    for (int e = 0; e < 8; ++e) acc[e] = 0.0;
    for (int d0 = 0; d0 < DDIM; d0 += 64) {
      float xs = xr[d0 + lane];
      const float4* wp = (const float4*)(wg + (size_t)(d0 + lane) * 8);
      float4 g0 = wp[0];
      float4 g1 = wp[1];
      double xd = (double)xs;
      acc[0] += xd * (double)g0.x; acc[1] += xd * (double)g0.y;
      acc[2] += xd * (double)g0.z; acc[3] += xd * (double)g0.w;
      acc[4] += xd * (double)g1.x; acc[5] += xd * (double)g1.y;
      acc[6] += xd * (double)g1.z; acc[7] += xd * (double)g1.w;
    }
#pragma unroll
    for (int e = 0; e < 8; ++e) {
      double v = acc[e];
      for (int off = 32; off > 0; off >>= 1) v += __shfl_down(v, off, 64);
      acc[e] = v;
    }
    if (lane == 0) {
      int e0 = 0; double l0 = acc[0];
      for (int e = 1; e < 8; ++e) if (acc[e] > l0) { l0 = acc[e]; e0 = e; }
      int e1 = -1; double l1 = -1e300;
      for (int e = 0; e < 8; ++e) if (e != e0 && acc[e] > l1) { l1 = acc[e]; e1 = e; }
      double pe = exp(l1 - l0);
      double inv = 1.0 / (1.0 + pe);
      eid[2 * s] = e0; eid[2 * s + 1] = e1;
      wts[2 * s] = (float)inv; wts[2 * s + 1] = (float)(pe * inv);
    }
    return;
  }
  if (bid < W1T_BLOCKS) {
    int e = bid >> 10, rem = bid & 1023;
    int d0 = (rem >> 5) << 6;
    int h0 = (rem & 31) << 6;
    const float* w1e = w1 + (size_t)e * DDIM * HDIM;
#pragma unroll
    for (int i = 0; i < 4; ++i) {
      int linear = i * 256 + tid;
      int r = linear >> 4, c4 = linear & 15;
      float4 v = *(const float4*)(w1e + (size_t)(d0 + r) * HDIM + h0 + c4 * 4);
      float* t = &tile[r * 65 + c4 * 4];
      t[0] = v.x; t[1] = v.y; t[2] = v.z; t[3] = v.w;
    }
    __syncthreads();
    f16* W1Te = W1T + (size_t)e * HDIM * DDIM;
#pragma unroll
    for (int i = 0; i < 2; ++i) {
      int linear = i * 256 + tid;
      int hr = linear >> 3, l8 = linear & 7;
      f16x8 o;
#pragma unroll
      for (int j = 0; j < 8; ++j) o[j] = (f16)tile[(l8 * 8 + j) * 65 + hr];
      *(f16x8*)(W1Te + (size_t)(h0 + hr) * DDIM + d0 + l8 * 8) = o;
    }
    return;
  }
  if (bid < W1T_BLOCKS + W2S_BLOCKS) {
    int wid = tid >> 6, lane = tid & 63;
    int row = (bid - W1T_BLOCKS) * 4 + wid;
    const float4* w24 = (const float4*)w2;
    float acc = 0.f;
    for (int j = 0; j < 8; ++j) {
      float4 v = w24[(size_t)row * 512 + j * 64 + lane];
      acc += v.x + v.y + v.z + v.w;
    }
    for (int off = 32; off > 0; off >>= 1) acc += __shfl_down(acc, off, 64);
    if (lane == 0) w2s[row] = acc;
    return;
  }
  {
    int e = tid >> 5, l32 = tid & 31;
    float acc = 0.f;
    for (int j = 0; j < 64; ++j) acc += b2[e * 2048 + j * 32 + l32];
    for (int off = 16; off > 0; off >>= 1) acc += __shfl_down(acc, off, 32);
    if (l32 == 0) b2s[e] = acc;
  }
}

// ---------------- capacity scan (deepspeed semantics): 16 waves, two-phase ----------------
__global__ __launch_bounds__(1024) void scan_kernel(const int* __restrict__ eid,
                                                    int* __restrict__ locb,
                                                    int* __restrict__ slot_token) {
  __shared__ int seg[16][2][8];
  __shared__ int base[16][2][8];
  int tid = threadIdx.x, wid = tid >> 6, lane = tid & 63;
  unsigned long long lower = (lane == 0) ? 0ull : ((~0ull) >> (64 - lane));
  const int2* eid2 = (const int2*)eid;
  int c0 = 0, c1 = 0;
  for (int r = 0; r < 8; ++r) {
    int2 ee = eid2[wid * 512 + r * 64 + lane];
#pragma unroll
    for (int e = 0; e < 8; ++e) {
      unsigned long long b0 = __ballot(ee.x == e);
      unsigned long long b1 = __ballot(ee.y == e);
      if (lane == e) { c0 += __popcll(b0); c1 += __popcll(b1); }
    }
  }
  if (lane < 8) { seg[wid][0][lane] = c0; seg[wid][1][lane] = c1; }
  __syncthreads();
  if (lane < 8) {
    int e = lane;
    int tot0 = 0;
#pragma unroll
    for (int w = 0; w < 16; ++w) tot0 += seg[w][0][e];
    int b0 = 0, b1 = tot0;
    for (int w = 0; w < wid; ++w) { b0 += seg[w][0][e]; b1 += seg[w][1][e]; }
    base[wid][0][e] = b0; base[wid][1][e] = b1;
  }
  for (int r = 0; r < 8; ++r) {
    int2 ee = eid2[wid * 512 + r * 64 + lane];
    int rank0 = 0, rank1 = 0, add0 = 0, add1 = 0;
#pragma unroll
    for (int e = 0; e < 8; ++e) {
      unsigned long long b0 = __ballot(ee.x == e);
      unsigned long long b1 = __ballot(ee.y == e);
      if (ee.x == e) rank0 = __popcll(b0 & lower);
      if (ee.y == e) rank1 = __popcll(b1 & lower);
      if (lane == e) { add0 = __popcll(b0); add1 = __popcll(b1); }
    }
    int loc0 = base[wid][0][ee.x] + rank0;
    int loc1 = base[wid][1][ee.y] + rank1;
    int s = wid * 512 + r * 64 + lane;
    int2 lo; lo.x = loc0; lo.y = loc1;
    *(int2*)&locb[2 * s] = lo;
    if (loc0 < CAP) slot_token[ee.x * CAP + loc0] = s;
    if (loc1 < CAP) slot_token[ee.y * CAP + loc1] = s;
    if (lane < 8) {
      atomicAdd(&base[wid][0][lane], add0);
      atomicAdd(&base[wid][1][lane], add1);
    }
  }
}

// ---------------- abuild: gather token rows into f16 [E,C,D], one slot per wave ----------------
__global__ __launch_bounds__(256) void abuild_kernel(const float* __restrict__ x,
                                                     const int* __restrict__ slot_token,
                                                     f16* __restrict__ A16) {
  int wid = threadIdx.x >> 6, lane = threadIdx.x & 63;
  int slot = blockIdx.x * 4 + wid;
  int s = slot_token[slot];
  const float4* x4 = (const float4*)x + (size_t)s * 512 + lane;
  f16x4* outp = (f16x4*)(A16 + (size_t)slot * DDIM) + lane;
#pragma unroll
  for (int i = 0; i < 8; ++i) {
    float4 xv = x4[i * 64];
    f16x4 h;
    h[0] = (f16)xv.x; h[1] = (f16)xv.y; h[2] = (f16)xv.z; h[3] = (f16)xv.w;
    outp[i * 64] = h;
  }
}

// ---------------- GEMM1: persistent 256-block, two 256x256 tiles per block ----------------
// R4 restructure: 2 barriers per K-tile + counted lgkm/vmcnt, within-tile pipelining.
// Mechanism: the old 4-lockstep-phase tile alternated LDS-read windows (~2260cy/CU) with
// MFMA windows (~2637cy/SIMD) -> 50% MfmaUtil. Now ds-read batches issue BEHIND the prior
// MFMA cluster (WAR-safe in program order) and drain via counted lgkmcnt at their consumer,
// so the 2 waves/SIMD drift between the (only) two barriers and LDS hides under MFMA issue.
// Residency protocol: stages ordered B,B,A,A at tile top; mid-tile vmcnt(4)+bar confirms
// B(T+1) for the fb0(T+1) cross-tile prefetch; vmcnt(0) at tile end confirms A(T+1)
// (those loads are ~3000cy old -> free). Per-wave vmcnt always precedes a barrier before
// any cross-wave LDS read (same discipline as the verified R3 close_w4+bar).

template <int MB, int NB>
__device__ __forceinline__ void quad_mfma(f32x4 (&acc)[8][4], const f16x8 (&av)[4][2],
                                          const f16x8 (&bv)[2][2]) {
#pragma unroll
  for (int mf = 0; mf < 4; ++mf)
#pragma unroll
    for (int nf = 0; nf < 2; ++nf) {
      f32x4 c = acc[MB + mf][NB + nf];
      c = __builtin_amdgcn_mfma_f32_16x16x32_f16(av[mf][0], bv[nf][0], c, 0, 0, 0);
      c = __builtin_amdgcn_mfma_f32_16x16x32_f16(av[mf][1], bv[nf][1], c, 0, 0, 0);
      acc[MB + mf][NB + nf] = c;
    }
}

__device__ __forceinline__ void lda4(f16x8 (&av)[4][2], const f16* p0, const f16* p1, int mh) {
#pragma unroll
  for (int mf = 0; mf < 4; ++mf) {
    av[mf][0] = *(const f16x8*)(p0 + (mh * 4 + mf) * 1024);
    av[mf][1] = *(const f16x8*)(p1 + (mh * 4 + mf) * 1024);
  }
}
__device__ __forceinline__ void ldb2(f16x8 (&bv)[2][2], const f16* p0, const f16* p1, int nh) {
#pragma unroll
  for (int nf = 0; nf < 2; ++nf) {
    bv[nf][0] = *(const f16x8*)(p0 + (nh * 2 + nf) * 1024);
    bv[nf][1] = *(const f16x8*)(p1 + (nh * 2 + nf) * 1024);
  }
}

// stage one 128-row half-tile; LDS dest linear, global source pre-swizzled (rule #21)
__device__ __forceinline__ void stage_half(const f16* tile_rows, f16* lds_region,
                                           int T, int h, int wl8, int wu8, int cs) {
#pragma unroll
  for (int i = 0; i < 2; ++i) {
    const f16* g = tile_rows + (size_t)(h * 128 + i * 64 + wl8) * DDIM + T * 64 + cs * 8;
    f16* d = lds_region + (h * 128 + i * 64 + wu8) * 64;
    __builtin_amdgcn_global_load_lds((gas_ptr)g, (las_ptr)d, 16, 0, 0);
  }
}

__device__ __forceinline__ void bar() {
  asm volatile("" ::: "memory");
  __builtin_amdgcn_s_barrier();
  asm volatile("" ::: "memory");
}
__device__ __forceinline__ void lgkm0sb() {
  asm volatile("s_waitcnt lgkmcnt(0)" ::: "memory");
  __builtin_amdgcn_sched_barrier(0);  // rule #18
}

// One K-tile. Reads bufR via {aRk0,aRk1,bRk0,bRk1}; stages T+1 into {stA,stB};
// prefetches fb0(T+1) from {nbk0,nbk1} (bufW). fb0 must hold tile T's n-half-0 on entry.
template <bool STAGE, bool PREF>
__device__ __forceinline__ void ktile(const f16* aRk0, const f16* aRk1,
                                      const f16* bRk0, const f16* bRk1,
                                      const f16* nbk0, const f16* nbk1,
                                      f16* stA, f16* stB,
                                      const f16* srcA, const f16* srcB, int Ta, int Tb,
                                      int wl8, int wu8, int cs,
                                      f16x8 (&fa)[4][2], f16x8 (&fb0)[2][2],
                                      f16x8 (&fb1)[2][2], f32x4 (&acc)[8][4]) {
  bar();  // all waves: bufW reads drained (c3-lgkm of T-1), all stages confirmed
  if (STAGE) {
    stage_half(srcB, stB, Tb, 0, wl8, wu8, cs);  // B first: mid-tile vmcnt(4) confirms B
    stage_half(srcB, stB, Tb, 1, wl8, wu8, cs);
    stage_half(srcA, stA, Ta, 0, wl8, wu8, cs);
    stage_half(srcA, stA, Ta, 1, wl8, wu8, cs);
  }
  lda4(fa, aRk0, aRk1, 0);
  lgkm0sb();  // fa(mh0) + fb0-prefetch leftovers drained
  __builtin_amdgcn_s_setprio(1);
  quad_mfma<0, 0>(acc, fa, fb0);
  __builtin_amdgcn_s_setprio(0);
  ldb2(fb1, bRk0, bRk1, 1);  // drains under c1 drift of sibling wave
  lgkm0sb();
  __builtin_amdgcn_s_setprio(1);
  quad_mfma<0, 2>(acc, fa, fb1);
  __builtin_amdgcn_s_setprio(0);
  lda4(fa, aRk0, aRk1, 1);  // WAR on fa keeps this below c2 (program order)
  lgkm0sb();
  __builtin_amdgcn_s_setprio(1);
  quad_mfma<4, 0>(acc, fa, fb0);  // fb0 last read here
  __builtin_amdgcn_s_setprio(0);
  if (STAGE) asm volatile("s_waitcnt vmcnt(4)" ::: "memory");  // B(T+1) landed (counted)
  bar();  // all waves confirmed B(T+1) -> prefetch below reads valid data
  if (PREF) ldb2(fb0, nbk0, nbk1, 0);  // fb0(T+1); drains under c4 / next lgkm
  __builtin_amdgcn_s_setprio(1);
  quad_mfma<4, 2>(acc, fa, fb1);
  __builtin_amdgcn_s_setprio(0);
  if (STAGE) asm volatile("s_waitcnt vmcnt(0)" ::: "memory");  // A(T+1): ~3000cy old, free
}

__device__ __forceinline__ void epilogue(f32x4 (&acc)[8][4], const float* __restrict__ b1,
                                         const float* __restrict__ w2s,
                                         float* __restrict__ zacc, int e, int c0, int h0,
                                         int wm, int wn, int quad, int l15) {
  float b1v[4], wsv[4];
#pragma unroll
  for (int nf = 0; nf < 4; ++nf) {
    int h = h0 + wn * 64 + nf * 16 + l15;
    b1v[nf] = b1[e * HDIM + h];
    wsv[nf] = w2s[e * HDIM + h];
  }
#pragma unroll
  for (int mf = 0; mf < 8; ++mf) {
    float pr[4];
#pragma unroll
    for (int rr = 0; rr < 4; ++rr) {
      float t = 0.f;
#pragma unroll
      for (int nf = 0; nf < 4; ++nf) {
        float v = acc[mf][nf][rr] + b1v[nf];
        t += (v > 0.f ? v : 0.f) * wsv[nf];
      }
      pr[rr] = t;
    }
#pragma unroll
    for (int rr = 0; rr < 4; ++rr)
#pragma unroll
      for (int off = 1; off < 16; off <<= 1) pr[rr] += __shfl_xor(pr[rr], off, 64);
    if (l15 == 0) {
      int m = c0 + wm * 128 + mf * 16 + quad * 4;
#pragma unroll
      for (int rr = 0; rr < 4; ++rr) atomicAdd(&zacc[e * CAP + m + rr], pr[rr]);
    }
  }
}

__global__ __launch_bounds__(512, 2) void gemm_kernel(const f16* __restrict__ A16,
                                                      const f16* __restrict__ W1T,
                                                      const float* __restrict__ b1,
                                                      const float* __restrict__ w2s,
                                                      float* __restrict__ zacc) {
  __shared__ __align__(16) f16 lds[4 * 256 * 64];  // 128 KiB
  const int tid = threadIdx.x;
  const int wid = tid >> 6, lane = tid & 63;
  const int wm = wid >> 2, wn = wid & 3;      // 2(M) x 4(N) wave grid, wave owns 128x64
  const int quad = lane >> 4, l15 = lane & 15;
  const int l3 = lane >> 3, c7 = lane & 7;
  const int cs = c7 ^ l3;                     // pre-swizzled source chunk
  const int wl8 = wid * 8 + l3, wu8 = wid * 8;

  int bid = blockIdx.x;
  int e = bid & 7;                            // one expert per XCD (round-robin dispatch)
  int idx = bid >> 3;                         // 0..31 within expert
  int cT = idx >> 2, hTp = idx & 3;
  int c0 = cT * 256;
  int h0a = hTp * 256, h0b = (hTp + 4) * 256;

  const f16* Abase = A16 + ((size_t)e * CAP + c0) * DDIM;
  const f16* Bbase0 = W1T + ((size_t)e * HDIM + h0a) * DDIM;
  const f16* Bbase1 = W1T + ((size_t)e * HDIM + h0b) * DDIM;

  f16* bufA0 = &lds[0];
  f16* bufB0 = &lds[16384];
  f16* bufA1 = &lds[2 * 16384];
  f16* bufB1 = &lds[3 * 16384];

  const int so0 = (quad ^ c7) * 8;
  const int so1 = ((quad + 4) ^ c7) * 8;
  const f16* a0k0 = bufA0 + (wm * 128 + l15) * 64 + so0;
  const f16* a0k1 = bufA0 + (wm * 128 + l15) * 64 + so1;
  const f16* a1k0 = a0k0 + 2 * 16384;
  const f16* a1k1 = a0k1 + 2 * 16384;
  const f16* b0k0 = bufB0 + (wn * 64 + l15) * 64 + so0;
  const f16* b0k1 = bufB0 + (wn * 64 + l15) * 64 + so1;
  const f16* b1k0 = b0k0 + 2 * 16384;
  const f16* b1k1 = b0k1 + 2 * 16384;

  f32x4 acc[8][4];
#pragma unroll
  for (int i = 0; i < 8; ++i)
#pragma unroll
    for (int jj = 0; jj < 4; ++jj) acc[i][jj] = (f32x4){0.f, 0.f, 0.f, 0.f};
  f16x8 fa[4][2], fb0[2][2], fb1[2][2];

  // prologue: stage T0 (B,B,A,A) -> buf0; drain; load fb0(T0)
  stage_half(Bbase0, bufB0, 0, 0, wl8, wu8, cs);
  stage_half(Bbase0, bufB0, 0, 1, wl8, wu8, cs);
  stage_half(Abase, bufA0, 0, 0, wl8, wu8, cs);
  stage_half(Abase, bufA0, 0, 1, wl8, wu8, cs);
  asm volatile("s_waitcnt vmcnt(0)" ::: "memory");
  bar();
  ldb2(fb0, b0k0, b0k1, 0);

  // ================= pass 0: output tile (c0, h0a) =================
#pragma unroll 1
  for (int it = 0; it < 15; ++it) {
    ktile<true, true>(a0k0, a0k1, b0k0, b0k1, b1k0, b1k1, bufA1, bufB1,
                      Abase, Bbase0, 2 * it + 1, 2 * it + 1, wl8, wu8, cs, fa, fb0, fb1, acc);
    ktile<true, true>(a1k0, a1k1, b1k0, b1k1, b0k0, b0k1, bufA0, bufB0,
                      Abase, Bbase0, 2 * it + 2, 2 * it + 2, wl8, wu8, cs, fa, fb0, fb1, acc);
  }
  // T30: stage T31 -> buf1
  ktile<true, true>(a0k0, a0k1, b0k0, b0k1, b1k0, b1k1, bufA1, bufB1,
                    Abase, Bbase0, 31, 31, wl8, wu8, cs, fa, fb0, fb1, acc);
  // T31: stage pass1-T0 -> buf0 (A panel identical, B switches to h0b); prefetch its fb0
  ktile<true, true>(a1k0, a1k1, b1k0, b1k1, b0k0, b0k1, bufA0, bufB0,
                    Abase, Bbase1, 0, 0, wl8, wu8, cs, fa, fb0, fb1, acc);

  epilogue(acc, b1, w2s, zacc, e, c0, h0a, wm, wn, quad, l15);
#pragma unroll
  for (int i = 0; i < 8; ++i)
#pragma unroll
    for (int jj = 0; jj < 4; ++jj) acc[i][jj] = (f32x4){0.f, 0.f, 0.f, 0.f};

  // ================= pass 1: output tile (c0, h0b) =================
#pragma unroll 1
  for (int it = 0; it < 15; ++it) {
    ktile<true, true>(a0k0, a0k1, b0k0, b0k1, b1k0, b1k1, bufA1, bufB1,
                      Abase, Bbase1, 2 * it + 1, 2 * it + 1, wl8, wu8, cs, fa, fb0, fb1, acc);
    ktile<true, true>(a1k0, a1k1, b1k0, b1k1, b0k0, b0k1, bufA0, bufB0,
                      Abase, Bbase1, 2 * it + 2, 2 * it + 2, wl8, wu8, cs, fa, fb0, fb1, acc);
  }
  // T30: stage T31 -> buf1
  ktile<true, true>(a0k0, a0k1, b0k0, b0k1, b1k0, b1k1, bufA1, bufB1,
                    Abase, Bbase1, 31, 31, wl8, wu8, cs, fa, fb0, fb1, acc);
  // T31 final: no stage, no prefetch
  ktile<false, false>(a1k0, a1k1, b1k0, b1k1, b0k0, b0k1, bufA0, bufB0,
                      Abase, Bbase1, 0, 0, wl8, wu8, cs, fa, fb0, fb1, acc);

  epilogue(acc, b1, w2s, zacc, e, c0, h0b, wm, wn, quad, l15);
}

// ---------------- fused combine + per-batch-row log_softmax ----------------
__global__ __launch_bounds__(1024) void tail_kernel(const int* __restrict__ eid,
                                                    const int* __restrict__ locb,
                                                    const float* __restrict__ wts,
                                                    const float* __restrict__ zacc,
                                                    const float* __restrict__ b2s,
                                                    float* __restrict__ out) {
  __shared__ float red[16];
  int b = blockIdx.x, tid = threadIdx.x;
  int wid = tid >> 6, lane = tid & 63;
  float v[2];
  float mx = -1e30f;
#pragma unroll
  for (int i = 0; i < 2; ++i) {
    int s = b * TT + i * 1024 + tid;
    float zz = 0.f;
#pragma unroll
    for (int k = 0; k < 2; ++k) {
      int e = eid[2 * s + k], loc = locb[2 * s + k];
      if (loc < CAP) zz += wts[2 * s + k] * (zacc[e * CAP + loc] + b2s[e]);
    }
    v[i] = zz;
    mx = fmaxf(mx, zz);
  }
  for (int off = 32; off > 0; off >>= 1) mx = fmaxf(mx, __shfl_xor(mx, off, 64));
  if (lane == 0) red[wid] = mx;
  __syncthreads();
  mx = red[0];
#pragma unroll
  for (int j = 1; j < 16; ++j) mx = fmaxf(mx, red[j]);
  float sum = expf(v[0] - mx) + expf(v[1] - mx);
  for (int off = 32; off > 0; off >>= 1) sum += __shfl_xor(sum, off, 64);
  __syncthreads();
  if (lane == 0) red[wid] = sum;
  __syncthreads();
  sum = 0.f;
#pragma unroll
  for (int j = 0; j < 16; ++j) sum += red[j];
  float lse = mx + logf(sum);
#pragma unroll
  for (int i = 0; i < 2; ++i) out[b * TT + i * 1024 + tid] = v[i] - lse;
}

extern "C" void kernel_launch(void* const* d_in, const int* in_sizes, int n_in,
                              void* d_out, int out_size, void* d_ws, size_t ws_size,
                              hipStream_t stream) {
  const float* x  = (const float*)d_in[0];
  const float* wg = (const float*)d_in[1];
  const float* w1 = (const float*)d_in[2];
  const float* b1 = (const float*)d_in[3];
  const float* w2 = (const float*)d_in[4];
  const float* b2 = (const float*)d_in[5];
  float* out = (float*)d_out;

  char* ws = (char*)d_ws;
  size_t off = 0;
  auto alloc = [&](size_t bytes) -> char* {
    char* p = ws + off;
    off += (bytes + 255) & ~(size_t)255;
    return p;
  };
  f16* A16 = (f16*)alloc((size_t)NE * CAP * DDIM * 2);
  f16* W1T = (f16*)alloc((size_t)NE * HDIM * DDIM * 2);
  float* w2s = (float*)alloc((size_t)NE * HDIM * 4);
  float* b2s = (float*)alloc(NE * 4);
  int* eid = (int*)alloc((size_t)S_TOK * 2 * 4);
  float* wts = (float*)alloc((size_t)S_TOK * 2 * 4);
  int* locb = (int*)alloc((size_t)S_TOK * 2 * 4);
  int* slot_token = (int*)alloc((size_t)NE * CAP * 4);
  float* zacc = (float*)alloc((size_t)NE * CAP * 4);
  if (off > ws_size) return;  // workspace too small: fail loudly via wrong output

  prep_kernel<<<K1_GRID, 256, 0, stream>>>(w1, w2, b2, x, wg, eid, wts, slot_token, zacc,
                                           W1T, w2s, b2s);
  scan_kernel<<<1, 1024, 0, stream>>>(eid, locb, slot_token);
  abuild_kernel<<<NE * CAP / 4, 256, 0, stream>>>(x, slot_token, A16);
  gemm_kernel<<<NE * 32, 512, 0, stream>>>(A16, W1T, b1, w2s, zacc);
  tail_kernel<<<NBATCH, 1024, 0, stream>>>(eid, locb, wts, zacc, b2s, out);
}